// Round 3
// baseline (517.852 us; speedup 1.0000x reference)
//
#include <hip/hip_runtime.h>
#include <hip/hip_bf16.h>

#define N_NODES 200000
#define KDIM 27
#define C_IN 32
#define C_OUT 32
#define REG_CNT 4
#define REG_SIZE 50000            // 50000 nodes * 64B = 3.2 MB < 4 MB L2/XCD
#define CONV_BLOCKS 3125          // 800000 threads, 8 floats each
#define PACK_BLOCKS 112           // 56*64*8 = 28672 threads
#define MAIN_WAVES 3125           // 6250 tiles / 2 tiles-per-wave

typedef __bf16 bf16x8 __attribute__((ext_vector_type(8)));
typedef float floatx4 __attribute__((ext_vector_type(4)));
typedef float float4_t __attribute__((ext_vector_type(4)));

__device__ inline bf16x8 zero_bf16x8() {
    bf16x8 z;
#pragma unroll
    for (int i = 0; i < 8; ++i) z[i] = (__bf16)0.0f;
    return z;
}

// Merged aux kernel.
// Blocks [0, CONV_BLOCKS): fp32 [N][32] -> bf16 [N][32] row-major (64B rows).
// Blocks [CONV_BLOCKS, +PACK_BLOCKS): pack weights into B-fragment groups:
//   g = (c*7 + t)*2 + tt ; wp[(g*64+lane)*8+j] = w[kk=4t+(lane>>4)][8c+j][tt*16+(lane&15)]
__global__ __launch_bounds__(256) void aux_kernel(
    const float* __restrict__ src, __bf16* __restrict__ dst,
    const float* __restrict__ w, __bf16* __restrict__ wp) {
    if (blockIdx.x < CONV_BLOCKS) {
        int i = blockIdx.x * 256 + threadIdx.x;     // < 800000 exact
        const float4_t* s = (const float4_t*)src;
        float4_t v0 = s[2 * i];
        float4_t v1 = s[2 * i + 1];
        bf16x8 o;
        o[0] = (__bf16)v0[0]; o[1] = (__bf16)v0[1];
        o[2] = (__bf16)v0[2]; o[3] = (__bf16)v0[3];
        o[4] = (__bf16)v1[0]; o[5] = (__bf16)v1[1];
        o[6] = (__bf16)v1[2]; o[7] = (__bf16)v1[3];
        ((bf16x8*)dst)[i] = o;
    } else {
        int id = (blockIdx.x - CONV_BLOCKS) * 256 + threadIdx.x;
        if (id >= 56 * 64 * 8) return;
        int j = id & 7;
        int lane = (id >> 3) & 63;
        int g = id >> 9;
        int tt = g & 1;
        int rest = g >> 1;
        int t = rest % 7;
        int c = rest / 7;
        int kk = 4 * t + (lane >> 4);
        int ch = 8 * c + j;
        int o  = tt * 16 + (lane & 15);
        wp[id] = (kk < KDIM) ? (__bf16)w[((size_t)kk * C_IN + ch) * C_OUT + o] : (__bf16)0.0f;
    }
}

// Main: persistent-ish grid (all blocks co-resident), 2 tiles (of 32 nodes) per wave.
// K-slot mapping per MFMA group (t,c): k = q*8+j <-> tap kk=4t+q, channel 8c+j.
// A-frag: A[m=lane&15][k]; C/D: col=lane&15, row=q*4+reg.
// Source-region passes: in pass r only indices in [r*50000,(r+1)*50000) are gathered,
// so the gather working set is 3.2 MB -> L2-resident per XCD.
__global__ __launch_bounds__(128, 4) void octconv_main_kernel(
    const int* __restrict__ neigh, const __bf16* __restrict__ data_bf,
    const __bf16* __restrict__ wpack, float* __restrict__ out) {
    int tid  = threadIdx.x;
    int wave_id = blockIdx.x * 2 + (tid >> 6);
    if (wave_id >= MAIN_WAVES) return;            // no barriers below: early-out safe
    int lane = tid & 63;
    int r16 = lane & 15;
    int q   = lane >> 4;

    // Preload neighbor indices for 2 tiles x 2 m-halves x 7 tap-groups (kk = 4t+q).
    int it0[2][7], it1[2][7];
#pragma unroll
    for (int tl = 0; tl < 2; ++tl) {
        int node_base = (wave_id * 2 + tl) * 32;
        const int* np0 = neigh + (size_t)(node_base + r16) * KDIM + q;
        const int* np1 = neigh + (size_t)(node_base + 16 + r16) * KDIM + q;
#pragma unroll
        for (int t = 0; t < 6; ++t) {
            it0[tl][t] = __builtin_nontemporal_load(np0 + 4 * t);
            it1[tl][t] = __builtin_nontemporal_load(np1 + 4 * t);
        }
        it0[tl][6] = (q == 3) ? -1 : __builtin_nontemporal_load(np0 + 24);
        it1[tl][6] = (q == 3) ? -1 : __builtin_nontemporal_load(np1 + 24);
    }

    floatx4 acc00[2], acc01[2], acc10[2], acc11[2];
#pragma unroll
    for (int tl = 0; tl < 2; ++tl) {
        acc00[tl] = (floatx4){0.f, 0.f, 0.f, 0.f};
        acc01[tl] = (floatx4){0.f, 0.f, 0.f, 0.f};
        acc10[tl] = (floatx4){0.f, 0.f, 0.f, 0.f};
        acc11[tl] = (floatx4){0.f, 0.f, 0.f, 0.f};
    }

    const bf16x8* wp8 = (const bf16x8*)wpack;

#pragma unroll 1
    for (int r = 0; r < REG_CNT; ++r) {
        unsigned lo = (unsigned)(r * REG_SIZE);
#pragma unroll
        for (int tl = 0; tl < 2; ++tl) {
#pragma unroll
            for (int t = 0; t < 7; ++t) {
                int i0 = it0[tl][t];
                int i1 = it1[tl][t];
                bool p0 = ((unsigned)i0 - lo) < (unsigned)REG_SIZE;   // -1 never matches
                bool p1 = ((unsigned)i1 - lo) < (unsigned)REG_SIZE;
                const bf16x8* row0 = (const bf16x8*)(data_bf + ((size_t)(unsigned)i0 << 5));
                const bf16x8* row1 = (const bf16x8*)(data_bf + ((size_t)(unsigned)i1 << 5));
#pragma unroll
                for (int c = 0; c < 4; ++c) {
                    bf16x8 a0 = zero_bf16x8();
                    bf16x8 a1 = zero_bf16x8();
                    if (p0) a0 = row0[c];
                    if (p1) a1 = row1[c];
                    int gb = ((c * 7 + t) * 2) * 64 + lane;
                    bf16x8 b0 = wp8[gb];
                    bf16x8 b1 = wp8[gb + 64];
                    acc00[tl] = __builtin_amdgcn_mfma_f32_16x16x32_bf16(a0, b0, acc00[tl], 0, 0, 0);
                    acc01[tl] = __builtin_amdgcn_mfma_f32_16x16x32_bf16(a0, b1, acc01[tl], 0, 0, 0);
                    acc10[tl] = __builtin_amdgcn_mfma_f32_16x16x32_bf16(a1, b0, acc10[tl], 0, 0, 0);
                    acc11[tl] = __builtin_amdgcn_mfma_f32_16x16x32_bf16(a1, b1, acc11[tl], 0, 0, 0);
                }
            }
        }
    }

    // Epilogue: C/D row = q*4 + reg, col = r16. Non-temporal (protect resident region).
#pragma unroll
    for (int tl = 0; tl < 2; ++tl) {
        int node_base = (wave_id * 2 + tl) * 32;
#pragma unroll
        for (int rr = 0; rr < 4; ++rr) {
            int row = q * 4 + rr;
            float* p0 = out + (size_t)(node_base + row) * C_OUT + r16;
            float* p1 = out + (size_t)(node_base + 16 + row) * C_OUT + r16;
            __builtin_nontemporal_store(acc00[tl][rr], p0);
            __builtin_nontemporal_store(acc01[tl][rr], p0 + 16);
            __builtin_nontemporal_store(acc10[tl][rr], p1);
            __builtin_nontemporal_store(acc11[tl][rr], p1 + 16);
        }
    }
}

extern "C" void kernel_launch(void* const* d_in, const int* in_sizes, int n_in,
                              void* d_out, int out_size, void* d_ws, size_t ws_size,
                              hipStream_t stream) {
    const float* data    = (const float*)d_in[0];   // [N, C_IN] fp32
    const float* weights = (const float*)d_in[1];   // [K, C_IN, C_OUT] fp32
    const int*   neigh   = (const int*)d_in[2];     // [N, K] int32
    float*       out     = (float*)d_out;           // [N, C_OUT] fp32

    __bf16* data_bf = (__bf16*)d_ws;                                      // 12.8 MB
    __bf16* wpack   = (__bf16*)((char*)d_ws + (size_t)N_NODES * C_IN * 2); // 57 KB

    hipLaunchKernelGGL(aux_kernel, dim3(CONV_BLOCKS + PACK_BLOCKS), dim3(256), 0, stream,
                       data, data_bf, weights, wpack);

    int blocks = (MAIN_WAVES + 1) / 2;   // 1563 blocks x 128 thr (2 waves) — all co-resident
    hipLaunchKernelGGL(octconv_main_kernel, dim3(blocks), dim3(128), 0, stream,
                       neigh, data_bf, wpack, out);
}

// Round 4
// 207.815 us; speedup vs baseline: 2.4919x; 2.4919x over previous
//
#include <hip/hip_runtime.h>
#include <hip/hip_bf16.h>

#define N_NODES 200000
#define KDIM 27
#define TAPS_PAD 28               // pad to even; tap 27 has idx=-1 (a=0) and zero weights
#define NGROUPS 14                // tap-pairs
#define C_IN 32
#define C_OUT 32
#define CONV_BLOCKS 3125          // 800000 threads, 8 floats each
#define PACK_BLOCKS 112           // 28*2*64*8 = 28672 threads

typedef __bf16 bf16x8 __attribute__((ext_vector_type(8)));
typedef float floatx4 __attribute__((ext_vector_type(4)));
typedef float float4_t __attribute__((ext_vector_type(4)));

__device__ inline bf16x8 zero_bf16x8() {
    bf16x8 z;
#pragma unroll
    for (int i = 0; i < 8; ++i) z[i] = (__bf16)0.0f;
    return z;
}

// Merged aux kernel.
// Blocks [0, CONV_BLOCKS): fp32 [N][32] -> bf16 [N][32] row-major (64B rows).
// Blocks [CONV_BLOCKS, +PACK_BLOCKS): pack weights, 28 taps (tap 27 zeroed):
//   wp[((kk*2+tt)*64+lane)*8+j] = w[kk][(lane>>4)*8+j][tt*16+(lane&15)]  (kk<27), else 0
__global__ __launch_bounds__(256) void aux_kernel(
    const float* __restrict__ src, __bf16* __restrict__ dst,
    const float* __restrict__ w, __bf16* __restrict__ wp) {
    if (blockIdx.x < CONV_BLOCKS) {
        int i = blockIdx.x * 256 + threadIdx.x;     // < 800000 exact
        const float4_t* s = (const float4_t*)src;
        float4_t v0 = s[2 * i];
        float4_t v1 = s[2 * i + 1];
        bf16x8 o;
        o[0] = (__bf16)v0[0]; o[1] = (__bf16)v0[1];
        o[2] = (__bf16)v0[2]; o[3] = (__bf16)v0[3];
        o[4] = (__bf16)v1[0]; o[5] = (__bf16)v1[1];
        o[6] = (__bf16)v1[2]; o[7] = (__bf16)v1[3];
        ((bf16x8*)dst)[i] = o;
    } else {
        int id = (blockIdx.x - CONV_BLOCKS) * 256 + threadIdx.x;
        if (id >= TAPS_PAD * 2 * 64 * 8) return;
        int j = id & 7;
        int lane = (id >> 3) & 63;
        int g = id >> 9;              // 0..55
        int tt = g & 1;
        int kk = g >> 1;              // 0..27
        int c = ((lane >> 4) << 3) + j;
        int o = tt * 16 + (lane & 15);
        wp[id] = (kk < KDIM) ? (__bf16)w[((size_t)kk * C_IN + c) * C_OUT + o] : (__bf16)0.0f;
    }
}

// Main: one wave = 32 nodes x 32 outputs. R1 layout:
// A-frag: A[m=lane&15][k=(lane>>4)*8+j] -> lane loads 16B at data[idx(m)] + (lane>>4)*8.
// 4 lanes share each 64B row-line, fully consumed.
// 3-stage pipeline over tap-pairs: idx(g+2) | gather(g+1) | mfma(g).
__global__ __launch_bounds__(256) void octconv_main_kernel(
    const int* __restrict__ neigh, const __bf16* __restrict__ data_bf,
    const __bf16* __restrict__ wpack, float* __restrict__ out) {
    int tid  = threadIdx.x;
    int lane = tid & 63;
    int wave_id = blockIdx.x * 4 + (tid >> 6);
    int node_base = wave_id * 32;
    int r16  = lane & 15;
    int half = lane >> 4;
    int cb   = half << 3;
    int m0 = node_base + r16;
    int m1 = m0 + 16;
    bool v0 = m0 < N_NODES;
    bool v1 = m1 < N_NODES;
    const int* np0 = neigh + (size_t)m0 * KDIM;
    const int* np1 = neigh + (size_t)m1 * KDIM;

    int   i0[2][2], i1[2][2];     // [group parity][tap in group]
    bf16x8 A0[2][2], A1[2][2];

    floatx4 acc00 = {0.f, 0.f, 0.f, 0.f};
    floatx4 acc01 = {0.f, 0.f, 0.f, 0.f};
    floatx4 acc10 = {0.f, 0.f, 0.f, 0.f};
    floatx4 acc11 = {0.f, 0.f, 0.f, 0.f};

    const bf16x8* wp8 = (const bf16x8*)wpack;

#define LOAD_IDX(g)                                                              \
    {                                                                            \
        int p_ = (g) & 1;                                                        \
        _Pragma("unroll")                                                        \
        for (int u_ = 0; u_ < 2; ++u_) {                                         \
            int kk_ = 2 * (g) + u_;                                              \
            bool tv_ = kk_ < KDIM;                                               \
            i0[p_][u_] = (v0 && tv_) ? __builtin_nontemporal_load(np0 + kk_) : -1; \
            i1[p_][u_] = (v1 && tv_) ? __builtin_nontemporal_load(np1 + kk_) : -1; \
        }                                                                        \
    }
#define GATHER(g)                                                                \
    {                                                                            \
        int p_ = (g) & 1;                                                        \
        _Pragma("unroll")                                                        \
        for (int u_ = 0; u_ < 2; ++u_) {                                         \
            int a_ = i0[p_][u_];                                                 \
            int b_ = i1[p_][u_];                                                 \
            bf16x8 x_ = zero_bf16x8();                                           \
            bf16x8 y_ = zero_bf16x8();                                           \
            if (a_ >= 0) x_ = *(const bf16x8*)(data_bf + ((size_t)(unsigned)a_ << 5) + cb); \
            if (b_ >= 0) y_ = *(const bf16x8*)(data_bf + ((size_t)(unsigned)b_ << 5) + cb); \
            A0[p_][u_] = x_;                                                     \
            A1[p_][u_] = y_;                                                     \
        }                                                                        \
    }

    // Prologue: fill the pipeline.
    LOAD_IDX(0);
    LOAD_IDX(1);
    GATHER(0);

#pragma unroll
    for (int g = 0; g < NGROUPS; ++g) {
        if (g + 2 < NGROUPS) LOAD_IDX(g + 2);
        if (g + 1 < NGROUPS) GATHER(g + 1);
        int p = g & 1;
#pragma unroll
        for (int u = 0; u < 2; ++u) {
            int kk = 2 * g + u;
            bf16x8 b0 = wp8[(kk * 2 + 0) * 64 + lane];
            bf16x8 b1 = wp8[(kk * 2 + 1) * 64 + lane];
            acc00 = __builtin_amdgcn_mfma_f32_16x16x32_bf16(A0[p][u], b0, acc00, 0, 0, 0);
            acc01 = __builtin_amdgcn_mfma_f32_16x16x32_bf16(A0[p][u], b1, acc01, 0, 0, 0);
            acc10 = __builtin_amdgcn_mfma_f32_16x16x32_bf16(A1[p][u], b0, acc10, 0, 0, 0);
            acc11 = __builtin_amdgcn_mfma_f32_16x16x32_bf16(A1[p][u], b1, acc11, 0, 0, 0);
        }
    }
#undef LOAD_IDX
#undef GATHER

    // Epilogue: C/D row = (lane>>4)*4 + reg, col = lane&15. Non-temporal stores.
#pragma unroll
    for (int r = 0; r < 4; ++r) {
        int row = half * 4 + r;
        int n0 = node_base + row;
        int n1 = n0 + 16;
        if (n0 < N_NODES) {
            float* p0 = out + (size_t)n0 * C_OUT + r16;
            __builtin_nontemporal_store(acc00[r], p0);
            __builtin_nontemporal_store(acc01[r], p0 + 16);
        }
        if (n1 < N_NODES) {
            float* p1 = out + (size_t)n1 * C_OUT + r16;
            __builtin_nontemporal_store(acc10[r], p1);
            __builtin_nontemporal_store(acc11[r], p1 + 16);
        }
    }
}

extern "C" void kernel_launch(void* const* d_in, const int* in_sizes, int n_in,
                              void* d_out, int out_size, void* d_ws, size_t ws_size,
                              hipStream_t stream) {
    const float* data    = (const float*)d_in[0];   // [N, C_IN] fp32
    const float* weights = (const float*)d_in[1];   // [K, C_IN, C_OUT] fp32
    const int*   neigh   = (const int*)d_in[2];     // [N, K] int32
    float*       out     = (float*)d_out;           // [N, C_OUT] fp32

    __bf16* data_bf = (__bf16*)d_ws;                                      // 12.8 MB
    __bf16* wpack   = (__bf16*)((char*)d_ws + (size_t)N_NODES * C_IN * 2); // 57 KB

    hipLaunchKernelGGL(aux_kernel, dim3(CONV_BLOCKS + PACK_BLOCKS), dim3(256), 0, stream,
                       data, data_bf, weights, wpack);

    // 6252 waves of 32 nodes (2-wave tail idles via guards); 1563 blocks x 256.
    hipLaunchKernelGGL(octconv_main_kernel, dim3(1563), dim3(256), 0, stream,
                       neigh, data_bf, wpack, out);
}